// Round 1
// baseline (84.922 us; speedup 1.0000x reference)
//
#include <hip/hip_runtime.h>

#define S_LEN 16384
#define L_LEN 16320
#define NF 32
#define PSTR 16448           // padded row stride for P (S_LEN+1 rounded up)
#define TWO_PI 6.283185307179586

// Kernel 0: sines[f][s] = amp[f] * sin(frequency[f]*19000*2pi*sr[s] + phases[f]*2pi)
// Computed in double: sin args reach ~7e4 rad; float32 arg rounding would cost
// ~4e-3 rad phase error. 524K double-sins, fully parallel -> negligible time.
__global__ __launch_bounds__(256) void sines_kernel(
    const float* __restrict__ sr, const float* __restrict__ phases,
    const float* __restrict__ amplitude, const float* __restrict__ frequency,
    float* __restrict__ sines)
{
    int i = blockIdx.x * 256 + threadIdx.x;   // grid is exact: 2048*256 = 32*16384
    int f = i >> 14;                          // S_LEN = 2^14
    int s = i & (S_LEN - 1);
    double arg = (double)frequency[f] * 19000.0 * TWO_PI * (double)sr[s]
               + (double)phases[f] * TWO_PI;
    sines[i] = (float)((double)amplitude[f] * sin(arg));
}

// Kernel 1: exclusive prefix sum per f-row, accumulated in double.
// P[f][s] = sum_{t<s} sines[f][t], s in [0, S_LEN].
__global__ __launch_bounds__(256) void scan_kernel(
    const float* __restrict__ sines, float* __restrict__ P)
{
    __shared__ double part[256];
    int f = blockIdx.x;
    const float* sf = sines + f * S_LEN;
    float* Pf = P + f * PSTR;
    int t = threadIdx.x;
    int base = t * 64;                        // 256 threads * 64 = 16384
    double lsum = 0.0;
    for (int j = 0; j < 64; ++j) lsum += (double)sf[base + j];
    part[t] = lsum;
    __syncthreads();
    if (t == 0) {
        double c = 0.0;
        for (int i = 0; i < 256; ++i) { double v = part[i]; part[i] = c; c += v; }
    }
    __syncthreads();
    double carry = part[t];
    for (int j = 0; j < 64; ++j) {
        Pf[base + j] = (float)carry;
        carry += (double)sf[base + j];
    }
    if (t == 255) Pf[S_LEN] = (float)carry;
}

// Kernel 2: out[b,l,f] = x[l+2f]*(P[l+32-f]-P[l])
//                      + x[l+2f+1]*(P[l+64-f]-P[l+32-f])
//                      + x[l+2f+2]*(P[l+65]-P[l+64-f])
//                      + x[l+32]*rk[f]
// Tile: 64 l-values x 32 f per block. P rows staged in LDS with stride 131
// (bank index (3f + i) % 32 -> conflict-free across lanes; diagonal reads are
// 2-way aliased which is free on gfx950).
__global__ __launch_bounds__(256) void conv_kernel(
    const float* __restrict__ x, const float* __restrict__ P,
    const float* __restrict__ rk, float* __restrict__ out)
{
    __shared__ float Pl[NF][131];   // 130 used, +1 pad
    __shared__ float xl[132];       // 130 used
    int b = blockIdx.y;
    int l0 = blockIdx.x * 64;
    int t = threadIdx.x;

    for (int idx = t; idx < NF * 130; idx += 256) {
        int f = idx / 130;
        int i = idx - f * 130;
        int s = l0 + i; if (s > S_LEN) s = S_LEN;      // clamp (value unused)
        Pl[f][i] = P[f * PSTR + s];
    }
    for (int idx = t; idx < 130; idx += 256) {
        int s = l0 + idx; if (s >= S_LEN) s = S_LEN - 1; // clamp (value unused)
        xl[idx] = x[b * S_LEN + s];
    }
    int f = t & 31;
    float rkf = rk[f];
    __syncthreads();

    int lb = t >> 5;   // 0..7
#pragma unroll
    for (int k = 0; k < 8; ++k) {
        int li = lb + k * 8;              // 0..63, each hit once
        float p0 = Pl[f][li];
        float p1 = Pl[f][li + 32 - f];
        float p2 = Pl[f][li + 64 - f];
        float p3 = Pl[f][li + 65];
        float xv0 = xl[li + 2 * f];
        float xv1 = xl[li + 2 * f + 1];
        float xv2 = xl[li + 2 * f + 2];
        float v = xv0 * (p1 - p0) + xv1 * (p2 - p1) + xv2 * (p3 - p2)
                + xl[li + 32] * rkf;
        int l = l0 + li;
        out[(b * L_LEN + l) * NF + f] = v;   // lanes 0..31 -> contiguous 128B
    }
}

extern "C" void kernel_launch(void* const* d_in, const int* in_sizes, int n_in,
                              void* d_out, int out_size, void* d_ws, size_t ws_size,
                              hipStream_t stream) {
    const float* x    = (const float*)d_in[0];  // (4, 16384, 1)
    const float* sr   = (const float*)d_in[1];  // (16384,)
    const float* ph   = (const float*)d_in[2];  // (32, 1)
    const float* amp  = (const float*)d_in[3];  // (32, 1)
    const float* freq = (const float*)d_in[4];  // (32, 1)
    const float* rk   = (const float*)d_in[5];  // (1, 1, 32)
    float* out = (float*)d_out;

    float* sines = (float*)d_ws;                // 32*16384 floats = 2 MB
    float* P     = sines + NF * S_LEN;          // 32*16448 floats ~= 2.1 MB

    sines_kernel<<<(NF * S_LEN) / 256, 256, 0, stream>>>(sr, ph, amp, freq, sines);
    scan_kernel<<<NF, 256, 0, stream>>>(sines, P);
    conv_kernel<<<dim3(L_LEN / 64, 4), 256, 0, stream>>>(x, P, rk, out);
}

// Round 2
// 78.738 us; speedup vs baseline: 1.0785x; 1.0785x over previous
//
#include <hip/hip_runtime.h>

#define S_LEN 16384
#define L_LEN 16320
#define NF 32
#define PSTR 16448           // padded row stride for P (S_LEN+1 rounded up)
#define TWO_PI 6.283185307179586

// Fused sines + per-f exclusive prefix scan.
// One block per f (32 blocks x 1024 threads); thread t owns samples
// [16t, 16t+16). Sine phase computed in double (args up to ~1.4e4 cycles;
// frac in double keeps phase error ~1e-12), then centered to [-pi,pi] and
// evaluated with fast-path sinf (~1 ulp). Scan: per-thread serial (double) ->
// wave shuffle scan (6 steps) -> 16 wave bases via LDS. No f64 libm sin, no
// global sines round-trip, no serial 256-chain.
__global__ __launch_bounds__(1024) void scan_kernel(
    const float* __restrict__ sr, const float* __restrict__ phases,
    const float* __restrict__ amplitude, const float* __restrict__ frequency,
    float* __restrict__ P)
{
    __shared__ double wsum[16];
    int f = blockIdx.x;
    int t = threadIdx.x;
    double fq = (double)frequency[f] * 19000.0;
    double ph = (double)phases[f];
    float amp = amplitude[f];
    int base = t * 16;
    float* Pf = P + f * PSTR;

    // 16 contiguous sr values via 4x float4 (64B-aligned)
    float4 sr4[4];
    const float4* sr4p = (const float4*)(sr + base);
#pragma unroll
    for (int q = 0; q < 4; ++q) sr4[q] = sr4p[q];
    const float* srv = (const float*)sr4;

    float sv[16];
    double lsum = 0.0;
#pragma unroll
    for (int j = 0; j < 16; ++j) {
        double u = fq * (double)srv[j] + ph;   // phase in revolutions
        u -= rint(u);                          // -> [-0.5, 0.5]
        float s = amp * sinf((float)(TWO_PI * u));
        sv[j] = s;
        lsum += (double)s;
    }

    // wave-level inclusive scan of per-thread sums (double)
    int lane = t & 63;
    double inc = lsum;
#pragma unroll
    for (int d = 1; d < 64; d <<= 1) {
        double up = __shfl_up(inc, d, 64);
        if (lane >= d) inc += up;
    }
    int wave = t >> 6;
    if (lane == 63) wsum[wave] = inc;          // wave total
    __syncthreads();
    if (t == 0) {
        double c = 0.0;
        for (int i = 0; i < 16; ++i) { double v = wsum[i]; wsum[i] = c; c += v; }
    }
    __syncthreads();

    // exclusive base for this thread's first element
    double excl = wsum[wave] + (inc - lsum);

    // write 16 P values as 4x float4
    float4 pv[4];
    float* pvf = (float*)pv;
    double run = excl;
#pragma unroll
    for (int j = 0; j < 16; ++j) {
        pvf[j] = (float)run;
        run += (double)sv[j];
    }
    float4* Pf4 = (float4*)(Pf + base);
#pragma unroll
    for (int q = 0; q < 4; ++q) Pf4[q] = pv[q];
    if (t == 1023) Pf[S_LEN] = (float)run;     // total
}

// Conv: out[b,l,f] = x[l+2f]*(P[l+32-f]-P[l])
//                  + x[l+2f+1]*(P[l+64-f]-P[l+32-f])
//                  + x[l+2f+2]*(P[l+65]-P[l+64-f])
//                  + x[l+32]*rk[f]
// Tile: 64 l x 32 f per block; P rows in LDS stride 131 (conflict-free
// diagonals, 2-way aliasing is free on gfx950); coalesced 128B output stores.
__global__ __launch_bounds__(256) void conv_kernel(
    const float* __restrict__ x, const float* __restrict__ P,
    const float* __restrict__ rk, float* __restrict__ out)
{
    __shared__ float Pl[NF][131];   // 130 used, +1 pad
    __shared__ float xl[132];       // 130 used
    int b = blockIdx.y;
    int l0 = blockIdx.x * 64;
    int t = threadIdx.x;

    for (int idx = t; idx < NF * 130; idx += 256) {
        int f = idx / 130;
        int i = idx - f * 130;
        int s = l0 + i; if (s > S_LEN) s = S_LEN;        // clamp (value unused)
        Pl[f][i] = P[f * PSTR + s];
    }
    for (int idx = t; idx < 130; idx += 256) {
        int s = l0 + idx; if (s >= S_LEN) s = S_LEN - 1; // clamp (value unused)
        xl[idx] = x[b * S_LEN + s];
    }
    int f = t & 31;
    float rkf = rk[f];
    __syncthreads();

    int lb = t >> 5;   // 0..7
#pragma unroll
    for (int k = 0; k < 8; ++k) {
        int li = lb + k * 8;              // 0..63, each hit once
        float p0 = Pl[f][li];
        float p1 = Pl[f][li + 32 - f];
        float p2 = Pl[f][li + 64 - f];
        float p3 = Pl[f][li + 65];
        float xv0 = xl[li + 2 * f];
        float xv1 = xl[li + 2 * f + 1];
        float xv2 = xl[li + 2 * f + 2];
        float v = xv0 * (p1 - p0) + xv1 * (p2 - p1) + xv2 * (p3 - p2)
                + xl[li + 32] * rkf;
        int l = l0 + li;
        out[(b * L_LEN + l) * NF + f] = v;   // lanes 0..31 -> contiguous 128B
    }
}

extern "C" void kernel_launch(void* const* d_in, const int* in_sizes, int n_in,
                              void* d_out, int out_size, void* d_ws, size_t ws_size,
                              hipStream_t stream) {
    const float* x    = (const float*)d_in[0];  // (4, 16384, 1)
    const float* sr   = (const float*)d_in[1];  // (16384,)
    const float* ph   = (const float*)d_in[2];  // (32, 1)
    const float* amp  = (const float*)d_in[3];  // (32, 1)
    const float* freq = (const float*)d_in[4];  // (32, 1)
    const float* rk   = (const float*)d_in[5];  // (1, 1, 32)
    float* out = (float*)d_out;

    float* P = (float*)d_ws;                    // 32*16448 floats ~= 2.1 MB

    scan_kernel<<<NF, 1024, 0, stream>>>(sr, ph, amp, freq, P);
    conv_kernel<<<dim3(L_LEN / 64, 4), 256, 0, stream>>>(x, P, rk, out);
}

// Round 3
// 72.247 us; speedup vs baseline: 1.1754x; 1.0898x over previous
//
#include <hip/hip_runtime.h>
#include <math.h>

#define S_LEN 16384
#define L_LEN 16320
#define NF 32
#define TWO_PI 6.283185307179586

// Single fused kernel. Derivation (validated numerically in R1/R2):
//   out[b,l,f] = x[l+2f]  * Sum_{t=l      ..l+31-f} sines[f][t]
//              + x[l+2f+1]* Sum_{t=l+32-f ..l+63-f} sines[f][t]
//              + x[l+2f+2]* Sum_{t=l+64-f ..l+64  } sines[f][t]
//              + x[l+32]  * rk[f]
// with sines[f][t] = amp*sin(2pi*(fq*t/16000 + ph)), an arithmetic phase
// progression -> each window sum has the closed (Dirichlet) form
//   Sum_{j<n} sin(p0 + w(a+j)) = sin(p0 + w*a + w(n-1)/2) * sin(n*w/2)/sin(w/2)
// so each term is A_w(f) * sin(2pi*(b_w(f) + nu(f)*l)), nu = fq/16000 rev/sample.
// Phase kept in double revolutions (|phase| up to ~1e4 rev; double keeps it to
// ~1e-12 rev), frac'd to [-0.5,0.5], then one fast-path sinf.
__global__ __launch_bounds__(256) void sineconv_kernel(
    const float* __restrict__ x, const float* __restrict__ phases,
    const float* __restrict__ amplitude, const float* __restrict__ frequency,
    const float* __restrict__ rk, float* __restrict__ out)
{
    __shared__ double c_nu[NF], c_b0[NF], c_b1[NF], c_b2[NF];
    __shared__ float c_A0[NF], c_A1[NF], c_A2[NF], c_rk[NF];
    __shared__ float xl[132];   // x[l0 .. l0+129]

    int b = blockIdx.y;
    int l0 = blockIdx.x * 64;
    int t = threadIdx.x;

    for (int idx = t; idx < 130; idx += 256) {
        int s = l0 + idx; if (s >= S_LEN) s = S_LEN - 1;  // clamp (value unused)
        xl[idx] = x[b * S_LEN + s];
    }

    if (t < NF) {
        int f = t;
        double fq  = (double)frequency[f] * 19000.0;
        double nu  = fq / 16000.0;             // revolutions per sample
        double om2 = (TWO_PI * 0.5) * nu;      // omega/2 (radians)
        double ph  = (double)phases[f];        // revolutions
        double amp = (double)amplitude[f];
        double sh  = sin(om2);
        int n0 = 32 - f, n2 = f + 1;
        double R0, R1, R2v;
        if (fabs(sh) > 1e-30) {
            double inv = 1.0 / sh;
            R0  = sin((double)n0 * om2) * inv;
            R1  = sin(32.0 * om2) * inv;
            R2v = sin((double)n2 * om2) * inv;
        } else {                               // degenerate freq (never hit here)
            R0 = n0; R1 = 32.0; R2v = n2;
        }
        c_nu[f] = nu;
        c_b0[f] = ph + nu * (0.5 * (double)(31 - f));          // start a=l,    n=32-f
        c_b1[f] = ph + nu * ((double)(32 - f) + 15.5);         // a=l+32-f,     n=32
        c_b2[f] = ph + nu * (64.0 - 0.5 * (double)f);          // a=l+64-f,     n=f+1
        c_A0[f] = (float)(amp * R0);
        c_A1[f] = (float)(amp * R1);
        c_A2[f] = (float)(amp * R2v);
        c_rk[f] = rk[f];
    }
    __syncthreads();

    int f = t & 31;
    double nu = c_nu[f];
    double b0 = c_b0[f], b1 = c_b1[f], b2 = c_b2[f];
    float A0 = c_A0[f], A1 = c_A1[f], A2 = c_A2[f], rkf = c_rk[f];
    int lb = t >> 5;   // 0..7; half-wave shares li -> broadcast LDS reads,
                       // xl[li+2f] stride-2 = 2-way aliasing (free on gfx950)

#pragma unroll
    for (int k = 0; k < 8; ++k) {
        int li = lb + k * 8;                  // 0..63, each hit once per block
        double lw = (double)(l0 + li);
        double u0 = fma(nu, lw, b0); u0 -= rint(u0);
        double u1 = fma(nu, lw, b1); u1 -= rint(u1);
        double u2 = fma(nu, lw, b2); u2 -= rint(u2);
        float s0 = A0 * sinf((float)u0 * (float)TWO_PI);
        float s1 = A1 * sinf((float)u1 * (float)TWO_PI);
        float s2 = A2 * sinf((float)u2 * (float)TWO_PI);
        float v = xl[li + 2*f] * s0 + xl[li + 2*f + 1] * s1 + xl[li + 2*f + 2] * s2
                + xl[li + 32] * rkf;
        out[((b * L_LEN) + (l0 + li)) * NF + f] = v;  // wave -> 256B contiguous
    }
}

extern "C" void kernel_launch(void* const* d_in, const int* in_sizes, int n_in,
                              void* d_out, int out_size, void* d_ws, size_t ws_size,
                              hipStream_t stream) {
    const float* x    = (const float*)d_in[0];  // (4, 16384, 1)
    // d_in[1] = sine_range: analytic (t/16000), not needed
    const float* ph   = (const float*)d_in[2];  // (32, 1)
    const float* amp  = (const float*)d_in[3];  // (32, 1)
    const float* freq = (const float*)d_in[4];  // (32, 1)
    const float* rk   = (const float*)d_in[5];  // (1, 1, 32)
    float* out = (float*)d_out;

    sineconv_kernel<<<dim3(L_LEN / 64, 4), 256, 0, stream>>>(x, ph, amp, freq, rk, out);
}